// Round 11
// baseline (576.854 us; speedup 1.0000x reference)
//
#include <hip/hip_runtime.h>
#include <math.h>

#define N_NODES 50000
#define N_EDGES 800000
#define D 128
#define NBLK 196   // ceil(N_NODES/256)

typedef __attribute__((ext_vector_type(8))) short bf16x8;
typedef __attribute__((ext_vector_type(4))) float f32x4;

static __device__ __forceinline__ unsigned short f2bf(float f) {
    unsigned int u = __float_as_uint(f);
    u = (u + 0x7fffu + ((u >> 16) & 1u)) >> 16;
    return (unsigned short)u;
}
static __device__ __forceinline__ float bf2f(unsigned short h) {
    return __uint_as_float(((unsigned int)h) << 16);
}

// ---------------- fused prep: degree histogram + split x + weight split-casts ----------------
// grid = 3125 (deg) + 6250 (split_x) + 64 (W1) + 64 (W2) + 48 (WL) = 9551 blocks, 256 thr
__global__ void prep_deg_kernel(const int* __restrict__ dst, int* __restrict__ deg,
                                const float* __restrict__ x,
                                const float* __restrict__ W1l, const float* __restrict__ W1r,
                                const float* __restrict__ W2l, const float* __restrict__ W2r,
                                const float* __restrict__ Wlin,
                                unsigned short* __restrict__ xhi, unsigned short* __restrict__ xlo,
                                unsigned short* __restrict__ W1hi, unsigned short* __restrict__ W1lo,
                                unsigned short* __restrict__ W2hi, unsigned short* __restrict__ W2lo,
                                unsigned short* __restrict__ WLhi, unsigned short* __restrict__ WLlo) {
    int b = blockIdx.x, tid = threadIdx.x;
    if (b < 3125) {
        int e = b * 256 + tid;
        atomicAdd(&deg[dst[e]], 1);
    } else if (b < 9375) {
        int i = ((b - 3125) * 256 + tid) * 4;
        float4 v = *(const float4*)(x + i);
        ushort4 h, l;
        h.x = f2bf(v.x); l.x = f2bf(v.x - bf2f(h.x));
        h.y = f2bf(v.y); l.y = f2bf(v.y - bf2f(h.y));
        h.z = f2bf(v.z); l.z = f2bf(v.z - bf2f(h.z));
        h.w = f2bf(v.w); l.w = f2bf(v.w - bf2f(h.w));
        *(ushort4*)(xhi + i) = h;
        *(ushort4*)(xlo + i) = l;
    } else if (b < 9503) {
        int isW2 = (b >= 9439);
        const float* A = isW2 ? W2l : W1l;
        const float* B = isW2 ? W2r : W1r;
        unsigned short* hi = isW2 ? W2hi : W1hi;
        unsigned short* lo = isW2 ? W2lo : W1lo;
        int f = (b - (isW2 ? 9439 : 9375)) * 2 + (tid >> 7);
        int t = tid & 127;
        float va = A[f * 128 + t], vb = B[f * 128 + t];
        unsigned short ha = f2bf(va), hb = f2bf(vb);
        hi[f * 256 + t]       = ha;
        hi[f * 256 + 128 + t] = hb;
        lo[f * 256 + t]       = f2bf(va - bf2f(ha));
        lo[f * 256 + 128 + t] = f2bf(vb - bf2f(hb));
    } else {
        int f = b - 9503;
        float v = (f < 40) ? Wlin[f * 256 + tid] : 0.f;
        unsigned short h = f2bf(v);
        WLhi[f * 256 + tid] = h;
        WLlo[f * 256 + tid] = f2bf(v - bf2f(h));
    }
}

// ---------------- 2-stage scan ----------------
__global__ void scan_partial(const int* __restrict__ deg, int* __restrict__ bsum) {
    __shared__ int wt[4];
    int tid = threadIdx.x, lane = tid & 63, wv = tid >> 6;
    int idx = blockIdx.x * 256 + tid;
    int v = (idx < N_NODES) ? deg[idx] : 0;
    int s = v;
    #pragma unroll
    for (int o = 1; o < 64; o <<= 1) s += __shfl_xor(s, o, 64);
    if (lane == 0) wt[wv] = s;
    __syncthreads();
    if (tid == 0) bsum[blockIdx.x] = wt[0] + wt[1] + wt[2] + wt[3];
}

__global__ void scan_write(const int* __restrict__ deg, const int* __restrict__ bsum,
                           int* __restrict__ rowptr, int* __restrict__ cursor) {
    __shared__ int wt[4], wt2[4];
    int tid = threadIdx.x, lane = tid & 63, wv = tid >> 6;
    int v0 = (tid < blockIdx.x) ? bsum[tid] : 0;   // blockIdx.x <= 195 < 256
    int s0 = v0;
    #pragma unroll
    for (int o = 1; o < 64; o <<= 1) s0 += __shfl_xor(s0, o, 64);
    if (lane == 0) wt2[wv] = s0;
    int idx = blockIdx.x * 256 + tid;
    int v = (idx < N_NODES) ? deg[idx] : 0;
    int s = v;
    #pragma unroll
    for (int o = 1; o < 64; o <<= 1) { int t = __shfl_up(s, o, 64); if (lane >= o) s += t; }
    if (lane == 63) wt[wv] = s;
    __syncthreads();
    int boff = wt2[0] + wt2[1] + wt2[2] + wt2[3];
    #pragma unroll
    for (int w = 0; w < 4; w++) boff += (w < wv) ? wt[w] : 0;
    int excl = boff + s - v;
    if (idx < N_NODES) { rowptr[idx] = excl; cursor[idx] = excl; }
    if (idx == 0) rowptr[N_NODES] = N_EDGES;
}

// ---------------- bucket edges by dst ----------------
__global__ void bucket_kernel(const int* __restrict__ src, const int* __restrict__ dst,
                              int* __restrict__ cursor, int* __restrict__ srcs_sorted) {
    int e = blockIdx.x * blockDim.x + threadIdx.x;
    if (e < N_EDGES) {
        int pos = atomicAdd(&cursor[dst[e]], 1);
        srcs_sorted[pos] = src[e];
    }
}

// ---------------- fused layer: streaming segmented gather (LDS) + split-bf16 MFMA GEMM ----------------
// Block = 512 thr (8 waves) = 64 nodes x 128 outputs. LDS ~68.6 KB -> 2 blocks/CU.
// Phase 1: wave wv streams the contiguous CSR edge range of nodes [nb0+wv*8, nb0+wv*8+8)
// in double-buffered 16-edge batches, flushing per-node means at segment boundaries.
// FINAL=true additionally fuses the 40-col classifier + log_softmax (h2 never hits HBM).
template<bool FINAL>
__global__ __launch_bounds__(512, 4) void fused_layer(
    const int* __restrict__ srcs, const int* __restrict__ rowptr,
    const unsigned short* __restrict__ Shi,                                     // gather source hi
    const unsigned short* __restrict__ A2hi, const unsigned short* __restrict__ A2lo,  // self planes
    const unsigned short* __restrict__ Whi, const unsigned short* __restrict__ Wlo,    // [128,256]
    const float* __restrict__ bias,
    unsigned short* __restrict__ Ohi, unsigned short* __restrict__ Olo,         // layer out (if !FINAL)
    const unsigned short* __restrict__ WLhi, const unsigned short* __restrict__ WLlo,  // [48,256]
    const float* __restrict__ blin, float* __restrict__ out)                    // (if FINAL)
{
    __shared__ unsigned int Ah[64 * 68];       // 17408 B (agg hi; reused as h2 hi if FINAL)
    __shared__ unsigned int Al[64 * 68];       // 17408 B
    __shared__ unsigned short Wl[16384];       // 32 KB (Whi half stage)
    __shared__ float stats[256];               // 1 KB softmax stats (FINAL)

    const int tid = threadIdx.x;
    const int wv = tid >> 6, lane = tid & 63;
    const int nb0 = blockIdx.x * 64;

    // ---- phase 1: streaming segmented gather-mean into LDS ----
    {
        const unsigned int* xp = (const unsigned int*)Shi;   // row = 64 dwords
        const int nstart = nb0 + wv * 8;
        int bnd[9];
        #pragma unroll
        for (int kk = 0; kk <= 8; kk++)
            bnd[kk] = rowptr[min(nstart + kk, N_NODES)];
        const int e0 = bnd[0], eEnd = bnd[8];
        float ax = 0.f, ay = 0.f;
        int k = 0;

        #define FLUSH_NODE()                                                        \
        {                                                                           \
            int dg = bnd[k + 1] - bnd[k];                                           \
            float inv = 1.0f / fmaxf((float)dg, 1.0f);                              \
            float sx = ax * inv, sy = ay * inv;                                     \
            unsigned short h0 = f2bf(sx), h1v = f2bf(sy);                           \
            unsigned short l0 = f2bf(sx - bf2f(h0)), l1v = f2bf(sy - bf2f(h1v));    \
            int nl = wv * 8 + k;                                                    \
            Ah[nl * 68 + lane] = (unsigned int)h0 | ((unsigned int)h1v << 16);      \
            Al[nl * 68 + lane] = (unsigned int)l0 | ((unsigned int)l1v << 16);      \
            ax = 0.f; ay = 0.f;                                                     \
        }

        const int nbatch = (eEnd - e0 + 15) >> 4;
        unsigned int u[2][16];

        #define ISSUE_BATCH(b, buf)                                                 \
        {                                                                           \
            int base_ = e0 + (b) * 16;                                              \
            _Pragma("unroll")                                                       \
            for (int j = 0; j < 16; j++) {                                          \
                int ee = min(base_ + j, N_EDGES - 1);                               \
                int s = srcs[ee];                                                   \
                u[buf][j] = xp[(size_t)s * 64 + lane];                              \
            }                                                                       \
        }

        if (nbatch > 0) ISSUE_BATCH(0, 0)
        #pragma unroll 1
        for (int b = 0; b < nbatch; b++) {
            if (b + 1 < nbatch) ISSUE_BATCH(b + 1, (b + 1) & 1)
            int base = e0 + b * 16;
            int cnt = min(16, eEnd - base);
            #pragma unroll
            for (int j = 0; j < 16; j++) {
                if (j >= cnt) break;
                while (k < 8 && base + j == bnd[k + 1]) { FLUSH_NODE() k++; }
                unsigned int uv = u[b & 1][j];
                ax += __uint_as_float(uv << 16);
                ay += __uint_as_float(uv & 0xffff0000u);
            }
        }
        while (k < 8) { FLUSH_NODE() k++; }
        #undef FLUSH_NODE
        #undef ISSUE_BATCH
    }
    __syncthreads();   // A tiles ready

    const int m = lane & 15, quad = lane >> 4;
    const int g = wv & 3, tp = wv >> 2;
    const int node_base = nb0 + g * 16;
    const int nodec = min(node_base + m, N_NODES - 1);

    // A1 frags (agg, K 0..127) from LDS; A2 frags (self, K 128..255) from global
    bf16x8 a1h[4], a1l[4], a2h[4], a2l[4];
    {
        const unsigned short* r2h = A2hi + (size_t)nodec * D + quad * 8;
        const unsigned short* r2l = A2lo + (size_t)nodec * D + quad * 8;
        #pragma unroll
        for (int ks = 0; ks < 4; ks++) {
            a2h[ks] = *(const bf16x8*)(r2h + ks * 32);
            a2l[ks] = *(const bf16x8*)(r2l + ks * 32);
        }
        #pragma unroll
        for (int ks = 0; ks < 4; ks++) {
            int ad = ((g * 16 + m) * 68 + quad * 4 + ks * 16) * 2;   // ushort offset
            a1h[ks] = *(const bf16x8*)((const unsigned short*)Ah + ad);
            a1l[ks] = *(const bf16x8*)((const unsigned short*)Al + ad);
        }
    }

    // ---- phase 2: GEMM over 2 f-halves (Whi staged 32 KB at a time) ----
    #pragma unroll 1
    for (int fh = 0; fh < 2; fh++) {
        const int f0 = fh * 64;
        if (fh) __syncthreads();
        #pragma unroll
        for (int itS = 0; itS < 4; itS++) {
            int c = tid + itS * 512;                 // 2048 chunks of 16B
            int nt = c >> 9, w2 = c & 511;
            int ks = w2 >> 6, lidx = w2 & 63;
            int mm = lidx >> 2, qq = lidx & 3;
            const unsigned short* gp = Whi + (size_t)(f0 + nt * 16 + mm) * 256 + ks * 32 + qq * 8;
            *(bf16x8*)&Wl[(size_t)c * 8] = *(const bf16x8*)gp;
        }
        __syncthreads();

        #pragma unroll
        for (int j = 0; j < 2; j++) {
            int ntl = tp * 2 + j;
            int f = f0 + ntl * 16 + m;
            const unsigned short* wlorow = Wlo + (size_t)f * 256 + quad * 8;
            f32x4 acc = {0.f, 0.f, 0.f, 0.f};
            #pragma unroll
            for (int ks = 0; ks < 8; ks++) {
                bf16x8 bh = *(const bf16x8*)&Wl[(size_t)(((ntl * 8 + ks) << 6) + (m * 4 + quad)) * 8];
                bf16x8 bl = *(const bf16x8*)(wlorow + ks * 32);
                bf16x8 ah = (ks < 4) ? a1h[ks] : a2h[ks - 4];
                bf16x8 al = (ks < 4) ? a1l[ks] : a2l[ks - 4];
                acc = __builtin_amdgcn_mfma_f32_16x16x32_bf16(ah, bh, acc, 0, 0, 0);
                acc = __builtin_amdgcn_mfma_f32_16x16x32_bf16(ah, bl, acc, 0, 0, 0);
                acc = __builtin_amdgcn_mfma_f32_16x16x32_bf16(al, bh, acc, 0, 0, 0);
            }
            float bv = bias[f];
            #pragma unroll
            for (int r = 0; r < 4; r++) {
                int lrow = g * 16 + quad * 4 + r;
                int nrow = nb0 + lrow;
                float v = fmaxf(acc[r] + bv, 0.f);
                unsigned short h = f2bf(v);
                unsigned short l = f2bf(v - bf2f(h));
                if (FINAL) {
                    ((unsigned short*)Ah)[lrow * 136 + f] = h;
                    ((unsigned short*)Al)[lrow * 136 + f] = l;
                } else if (nrow < N_NODES) {
                    Ohi[(size_t)nrow * D + f] = h;
                    Olo[(size_t)nrow * D + f] = l;
                }
            }
        }
    }

    if (!FINAL) return;

    // ---- phase 3: classifier GEMM (48 cols) + log_softmax ----
    __syncthreads();   // h2 LDS complete
    bf16x8 a3h[4], a3l[4];
    #pragma unroll
    for (int ks = 0; ks < 4; ks++) {
        int ad = (g * 16 + m) * 136 + ks * 32 + quad * 8;
        a3h[ks] = *(const bf16x8*)((const unsigned short*)Ah + ad);
        a3l[ks] = *(const bf16x8*)((const unsigned short*)Al + ad);
    }
    const int ntiles = (tp == 0) ? 2 : 1;
    float res[2][4];
    #pragma unroll
    for (int t = 0; t < 2; t++) {
        if (t >= ntiles) break;
        int nt = (tp == 0) ? t : 2;
        int f = nt * 16 + m;
        const unsigned short* whirow = WLhi + (size_t)f * 256 + quad * 8;
        const unsigned short* wlorow = WLlo + (size_t)f * 256 + quad * 8;
        f32x4 acc = {0.f, 0.f, 0.f, 0.f};
        #pragma unroll
        for (int ks = 0; ks < 8; ks++) {
            bf16x8 bh = *(const bf16x8*)(whirow + ks * 32);
            bf16x8 bl = *(const bf16x8*)(wlorow + ks * 32);
            bf16x8 ah = (ks < 4) ? a2h[ks] : a3h[ks - 4];   // A = [h1 | h2]
            bf16x8 al = (ks < 4) ? a2l[ks] : a3l[ks - 4];
            acc = __builtin_amdgcn_mfma_f32_16x16x32_bf16(ah, bh, acc, 0, 0, 0);
            acc = __builtin_amdgcn_mfma_f32_16x16x32_bf16(ah, bl, acc, 0, 0, 0);
            acc = __builtin_amdgcn_mfma_f32_16x16x32_bf16(al, bh, acc, 0, 0, 0);
        }
        float bv = (f < 40) ? blin[f] : 0.f;
        #pragma unroll
        for (int r = 0; r < 4; r++) res[t][r] = acc[r] + bv;
    }
    #pragma unroll
    for (int r = 0; r < 4; r++) {
        float pm = -INFINITY;
        #pragma unroll
        for (int t = 0; t < 2; t++) {
            if (t >= ntiles) break;
            int f = ((tp == 0) ? t : 2) * 16 + m;
            if (f < 40) pm = fmaxf(pm, res[t][r]);
        }
        #pragma unroll
        for (int o = 8; o > 0; o >>= 1) pm = fmaxf(pm, __shfl_xor(pm, o, 64));
        if (m == 0) stats[tp * 64 + g * 16 + quad * 4 + r] = pm;
    }
    __syncthreads();
    float gm[4];
    #pragma unroll
    for (int r = 0; r < 4; r++) {
        int row = g * 16 + quad * 4 + r;
        gm[r] = fmaxf(stats[row], stats[64 + row]);
        float ps = 0.f;
        #pragma unroll
        for (int t = 0; t < 2; t++) {
            if (t >= ntiles) break;
            int f = ((tp == 0) ? t : 2) * 16 + m;
            if (f < 40) ps += expf(res[t][r] - gm[r]);
        }
        #pragma unroll
        for (int o = 8; o > 0; o >>= 1) ps += __shfl_xor(ps, o, 64);
        if (m == 0) stats[128 + tp * 64 + row] = ps;
    }
    __syncthreads();
    #pragma unroll
    for (int r = 0; r < 4; r++) {
        int row = g * 16 + quad * 4 + r;
        int nrow = nb0 + row;
        if (nrow >= N_NODES) continue;
        float lse = gm[r] + logf(stats[128 + row] + stats[192 + row]);
        #pragma unroll
        for (int t = 0; t < 2; t++) {
            if (t >= ntiles) break;
            int f = ((tp == 0) ? t : 2) * 16 + m;
            if (f < 40) out[(size_t)nrow * 40 + f] = res[t][r] - lse;
        }
    }
}

extern "C" void kernel_launch(void* const* d_in, const int* in_sizes, int n_in,
                              void* d_out, int out_size, void* d_ws, size_t ws_size,
                              hipStream_t stream) {
    const float* x     = (const float*)d_in[0];
    const int*   ei    = (const int*)d_in[1];
    const int*   src   = ei;
    const int*   dst   = ei + N_EDGES;
    const float* W1_l  = (const float*)d_in[2];
    const float* b1_l  = (const float*)d_in[3];
    const float* W1_r  = (const float*)d_in[4];
    const float* W2_l  = (const float*)d_in[5];
    const float* b2_l  = (const float*)d_in[6];
    const float* W2_r  = (const float*)d_in[7];
    const float* W_lin = (const float*)d_in[8];
    const float* b_lin = (const float*)d_in[9];
    float* out = (float*)d_out;

    const size_t nd = (size_t)N_NODES * D;
    unsigned short* xhi  = (unsigned short*)d_ws;
    unsigned short* xlo  = xhi + nd;
    unsigned short* h1hi = xlo + nd;
    unsigned short* h1lo = h1hi + nd;
    unsigned short* W1hi = h1lo + nd;                // 128*256 bf16 each
    unsigned short* W1lo = W1hi + 128 * 256;
    unsigned short* W2hi = W1lo + 128 * 256;
    unsigned short* W2lo = W2hi + 128 * 256;
    unsigned short* WLhi = W2lo + 128 * 256;         // 48*256
    unsigned short* WLlo = WLhi + 48 * 256;
    int* deg    = (int*)(WLlo + 48 * 256);
    int* rowptr = deg + N_NODES;
    int* cursor = rowptr + N_NODES + 1;
    int* srcs_sorted = cursor + N_NODES;
    int* bsum   = srcs_sorted + N_EDGES;             // NBLK ints

    // ---- prep (casts/splits) + degree histogram in one dispatch ----
    hipMemsetAsync(deg, 0, N_NODES * sizeof(int), stream);
    prep_deg_kernel<<<9551, 256, 0, stream>>>(dst, deg, x, W1_l, W1_r, W2_l, W2_r, W_lin,
                                              xhi, xlo, W1hi, W1lo, W2hi, W2lo, WLhi, WLlo);

    // ---- CSR build ----
    scan_partial<<<NBLK, 256, 0, stream>>>(deg, bsum);
    scan_write<<<NBLK, 256, 0, stream>>>(deg, bsum, rowptr, cursor);
    bucket_kernel<<<(N_EDGES + 255) / 256, 256, 0, stream>>>(src, dst, cursor, srcs_sorted);

    const int lblk = (N_NODES + 63) / 64;

    // ---- layer 1: gather(x) + GEMM -> h1 planes ----
    fused_layer<false><<<lblk, 512, 0, stream>>>(srcs_sorted, rowptr, xhi, xhi, xlo,
                                                 W1hi, W1lo, b1_l, h1hi, h1lo,
                                                 nullptr, nullptr, nullptr, nullptr);
    // ---- layer 2 + classifier + log_softmax (h2 stays in LDS) ----
    fused_layer<true><<<lblk, 512, 0, stream>>>(srcs_sorted, rowptr, h1hi, h1hi, h1lo,
                                                W2hi, W2lo, b2_l, nullptr, nullptr,
                                                WLhi, WLlo, b_lin, out);
}

// Round 12
// 373.084 us; speedup vs baseline: 1.5462x; 1.5462x over previous
//
#include <hip/hip_runtime.h>
#include <math.h>

#define N_NODES 50000
#define N_EDGES 800000
#define D 128
#define NBLK 196   // ceil(N_NODES/256)

typedef __attribute__((ext_vector_type(8))) short bf16x8;
typedef __attribute__((ext_vector_type(4))) float f32x4;

static __device__ __forceinline__ unsigned short f2bf(float f) {
    unsigned int u = __float_as_uint(f);
    u = (u + 0x7fffu + ((u >> 16) & 1u)) >> 16;
    return (unsigned short)u;
}
static __device__ __forceinline__ float bf2f(unsigned short h) {
    return __uint_as_float(((unsigned int)h) << 16);
}

// ---------------- fused prep: degree histogram + split x + weight split-casts ----------------
__global__ void prep_deg_kernel(const int* __restrict__ dst, int* __restrict__ deg,
                                const float* __restrict__ x,
                                const float* __restrict__ W1l, const float* __restrict__ W1r,
                                const float* __restrict__ W2l, const float* __restrict__ W2r,
                                const float* __restrict__ Wlin,
                                unsigned short* __restrict__ xhi, unsigned short* __restrict__ xlo,
                                unsigned short* __restrict__ W1hi, unsigned short* __restrict__ W1lo,
                                unsigned short* __restrict__ W2hi, unsigned short* __restrict__ W2lo,
                                unsigned short* __restrict__ WLhi, unsigned short* __restrict__ WLlo) {
    int b = blockIdx.x, tid = threadIdx.x;
    if (b < 3125) {
        int e = b * 256 + tid;
        atomicAdd(&deg[dst[e]], 1);
    } else if (b < 9375) {
        int i = ((b - 3125) * 256 + tid) * 4;
        float4 v = *(const float4*)(x + i);
        ushort4 h, l;
        h.x = f2bf(v.x); l.x = f2bf(v.x - bf2f(h.x));
        h.y = f2bf(v.y); l.y = f2bf(v.y - bf2f(h.y));
        h.z = f2bf(v.z); l.z = f2bf(v.z - bf2f(h.z));
        h.w = f2bf(v.w); l.w = f2bf(v.w - bf2f(h.w));
        *(ushort4*)(xhi + i) = h;
        *(ushort4*)(xlo + i) = l;
    } else if (b < 9503) {
        int isW2 = (b >= 9439);
        const float* A = isW2 ? W2l : W1l;
        const float* B = isW2 ? W2r : W1r;
        unsigned short* hi = isW2 ? W2hi : W1hi;
        unsigned short* lo = isW2 ? W2lo : W1lo;
        int f = (b - (isW2 ? 9439 : 9375)) * 2 + (tid >> 7);
        int t = tid & 127;
        float va = A[f * 128 + t], vb = B[f * 128 + t];
        unsigned short ha = f2bf(va), hb = f2bf(vb);
        hi[f * 256 + t]       = ha;
        hi[f * 256 + 128 + t] = hb;
        lo[f * 256 + t]       = f2bf(va - bf2f(ha));
        lo[f * 256 + 128 + t] = f2bf(vb - bf2f(hb));
    } else {
        int f = b - 9503;
        float v = (f < 40) ? Wlin[f * 256 + tid] : 0.f;
        unsigned short h = f2bf(v);
        WLhi[f * 256 + tid] = h;
        WLlo[f * 256 + tid] = f2bf(v - bf2f(h));
    }
}

// ---------------- 2-stage scan ----------------
__global__ void scan_partial(const int* __restrict__ deg, int* __restrict__ bsum) {
    __shared__ int wt[4];
    int tid = threadIdx.x, lane = tid & 63, wv = tid >> 6;
    int idx = blockIdx.x * 256 + tid;
    int v = (idx < N_NODES) ? deg[idx] : 0;
    int s = v;
    #pragma unroll
    for (int o = 1; o < 64; o <<= 1) s += __shfl_xor(s, o, 64);
    if (lane == 0) wt[wv] = s;
    __syncthreads();
    if (tid == 0) bsum[blockIdx.x] = wt[0] + wt[1] + wt[2] + wt[3];
}

__global__ void scan_write(const int* __restrict__ deg, const int* __restrict__ bsum,
                           int* __restrict__ rowptr, int* __restrict__ cursor) {
    __shared__ int wt[4], wt2[4];
    int tid = threadIdx.x, lane = tid & 63, wv = tid >> 6;
    int v0 = (tid < blockIdx.x) ? bsum[tid] : 0;   // blockIdx.x <= 195 < 256
    int s0 = v0;
    #pragma unroll
    for (int o = 1; o < 64; o <<= 1) s0 += __shfl_xor(s0, o, 64);
    if (lane == 0) wt2[wv] = s0;
    int idx = blockIdx.x * 256 + tid;
    int v = (idx < N_NODES) ? deg[idx] : 0;
    int s = v;
    #pragma unroll
    for (int o = 1; o < 64; o <<= 1) { int t = __shfl_up(s, o, 64); if (lane >= o) s += t; }
    if (lane == 63) wt[wv] = s;
    __syncthreads();
    int boff = wt2[0] + wt2[1] + wt2[2] + wt2[3];
    #pragma unroll
    for (int w = 0; w < 4; w++) boff += (w < wv) ? wt[w] : 0;
    int excl = boff + s - v;
    if (idx < N_NODES) { rowptr[idx] = excl; cursor[idx] = excl; }
    if (idx == 0) rowptr[N_NODES] = N_EDGES;
}

// ---------------- bucket edges by dst ----------------
__global__ void bucket_kernel(const int* __restrict__ src, const int* __restrict__ dst,
                              int* __restrict__ cursor, int* __restrict__ srcs_sorted) {
    int e = blockIdx.x * blockDim.x + threadIdx.x;
    if (e < N_EDGES) {
        int pos = atomicAdd(&cursor[dst[e]], 1);
        srcs_sorted[pos] = src[e];
    }
}

// ---------------- fused layer: gather-mean (LDS) + split-bf16 MFMA GEMM ----------------
// Block = 512 thr (8 waves) = 64 nodes x 128 outputs. LDS 51 KB -> 3 blocks/CU.
// launch_bounds(512,4): VGPR budget 128 (the round-9 (512,6)/VGPR-40 squeeze regressed).
// Gather: per node, full 16-batches then ONE clamped+masked 16-batch remainder
// (static indexing only — round-11's dynamically-indexed dbuf spilled to scratch).
// FINAL=true additionally fuses the 40-col classifier + log_softmax (h2 never hits HBM).
template<bool FINAL>
__global__ __launch_bounds__(512, 4) void fused_layer(
    const int* __restrict__ srcs, const int* __restrict__ rowptr,
    const unsigned short* __restrict__ Shi,                                     // gather source hi
    const unsigned short* __restrict__ A2hi, const unsigned short* __restrict__ A2lo,  // self planes
    const unsigned short* __restrict__ Whi, const unsigned short* __restrict__ Wlo,    // [128,256]
    const float* __restrict__ bias,
    unsigned short* __restrict__ Ohi, unsigned short* __restrict__ Olo,         // layer out (if !FINAL)
    const unsigned short* __restrict__ WLhi, const unsigned short* __restrict__ WLlo,  // [48,256]
    const float* __restrict__ blin, float* __restrict__ out)                    // (if FINAL)
{
    __shared__ unsigned int Ah[64 * 68];       // 17408 B (agg hi; reused as h2 hi if FINAL)
    __shared__ unsigned int Al[64 * 68];       // 17408 B
    __shared__ unsigned short Wl[8192];        // 16 KB (Whi quarter stage)
    __shared__ float stats[256];               // 1 KB softmax stats (FINAL)

    const int tid = threadIdx.x;
    const int wv = tid >> 6, lane = tid & 63;
    const int nb0 = blockIdx.x * 64;

    // ---- phase 1: gather-mean into LDS (hi-plane source) ----
    const unsigned int* xp = (const unsigned int*)Shi;   // row = 64 dwords
    for (int it = 0; it < 8; it++) {
        int nl = it * 8 + wv;
        int node = min(nb0 + nl, N_NODES - 1);
        int beg = rowptr[node], end = rowptr[node + 1];
        float ax[8] = {0,0,0,0,0,0,0,0}, ay[8] = {0,0,0,0,0,0,0,0};
        int i = beg;
        for (; i + 16 <= end; i += 16) {
            unsigned int u[16];
            #pragma unroll
            for (int j = 0; j < 16; j++) u[j] = xp[(size_t)srcs[i + j] * 64 + lane];
            #pragma unroll
            for (int j = 0; j < 16; j++) {
                ax[j & 7] += __uint_as_float(u[j] << 16);
                ay[j & 7] += __uint_as_float(u[j] & 0xffff0000u);
            }
        }
        int r = end - i;
        if (r > 0) {
            // clamped + masked 16-batch: duplicates hit L1; mask drops them
            unsigned int u[16];
            #pragma unroll
            for (int j = 0; j < 16; j++) {
                int ee = min(i + j, end - 1);
                u[j] = xp[(size_t)srcs[ee] * 64 + lane];
            }
            #pragma unroll
            for (int j = 0; j < 16; j++) {
                if (j < r) {
                    ax[j & 7] += __uint_as_float(u[j] << 16);
                    ay[j & 7] += __uint_as_float(u[j] & 0xffff0000u);
                }
            }
        }
        float sx = ((ax[0] + ax[1]) + (ax[2] + ax[3])) + ((ax[4] + ax[5]) + (ax[6] + ax[7]));
        float sy = ((ay[0] + ay[1]) + (ay[2] + ay[3])) + ((ay[4] + ay[5]) + (ay[6] + ay[7]));
        float inv = 1.0f / fmaxf((float)(end - beg), 1.0f);
        sx *= inv; sy *= inv;
        unsigned short h0 = f2bf(sx), h1 = f2bf(sy);
        unsigned short l0 = f2bf(sx - bf2f(h0)), l1 = f2bf(sy - bf2f(h1));
        Ah[nl * 68 + lane] = (unsigned int)h0 | ((unsigned int)h1 << 16);
        Al[nl * 68 + lane] = (unsigned int)l0 | ((unsigned int)l1 << 16);
    }
    __syncthreads();   // A tiles ready

    const int m = lane & 15, quad = lane >> 4;
    const int g = wv & 3, tp = wv >> 2;
    const int node_base = nb0 + g * 16;
    const int nodec = min(node_base + m, N_NODES - 1);

    // A1 frags (agg, K 0..127) from LDS; A2 frags (self, K 128..255) from global
    bf16x8 a1h[4], a1l[4], a2h[4], a2l[4];
    {
        const unsigned short* r2h = A2hi + (size_t)nodec * D + quad * 8;
        const unsigned short* r2l = A2lo + (size_t)nodec * D + quad * 8;
        #pragma unroll
        for (int ks = 0; ks < 4; ks++) {
            a2h[ks] = *(const bf16x8*)(r2h + ks * 32);
            a2l[ks] = *(const bf16x8*)(r2l + ks * 32);
        }
        #pragma unroll
        for (int ks = 0; ks < 4; ks++) {
            int ad = ((g * 16 + m) * 68 + quad * 4 + ks * 16) * 2;   // ushort offset
            a1h[ks] = *(const bf16x8*)((const unsigned short*)Ah + ad);
            a1l[ks] = *(const bf16x8*)((const unsigned short*)Al + ad);
        }
    }

    // ---- phase 2: GEMM over 4 f-quarters (Whi staged 16 KB at a time) ----
    #pragma unroll 1
    for (int fq = 0; fq < 4; fq++) {
        const int f0 = fq * 32;
        if (fq) __syncthreads();
        #pragma unroll
        for (int itS = 0; itS < 2; itS++) {
            int c = tid + itS * 512;                 // 1024 chunks of 16B
            int nt = c >> 9, w2 = c & 511;
            int ks = w2 >> 6, lidx = w2 & 63;
            int mm = lidx >> 2, qq = lidx & 3;
            const unsigned short* gp = Whi + (size_t)(f0 + nt * 16 + mm) * 256 + ks * 32 + qq * 8;
            *(bf16x8*)&Wl[(size_t)c * 8] = *(const bf16x8*)gp;
        }
        __syncthreads();

        int f = f0 + tp * 16 + m;
        const unsigned short* wlorow = Wlo + (size_t)f * 256 + quad * 8;
        f32x4 acc = {0.f, 0.f, 0.f, 0.f};
        #pragma unroll
        for (int ks = 0; ks < 8; ks++) {
            bf16x8 bh = *(const bf16x8*)&Wl[(size_t)(((tp * 8 + ks) << 6) + (m * 4 + quad)) * 8];
            bf16x8 bl = *(const bf16x8*)(wlorow + ks * 32);
            bf16x8 ah = (ks < 4) ? a1h[ks] : a2h[ks - 4];
            bf16x8 al = (ks < 4) ? a1l[ks] : a2l[ks - 4];
            acc = __builtin_amdgcn_mfma_f32_16x16x32_bf16(ah, bh, acc, 0, 0, 0);
            acc = __builtin_amdgcn_mfma_f32_16x16x32_bf16(ah, bl, acc, 0, 0, 0);
            acc = __builtin_amdgcn_mfma_f32_16x16x32_bf16(al, bh, acc, 0, 0, 0);
        }
        float bv = bias[f];
        #pragma unroll
        for (int r = 0; r < 4; r++) {
            int lrow = g * 16 + quad * 4 + r;
            int nrow = nb0 + lrow;
            float v = fmaxf(acc[r] + bv, 0.f);
            unsigned short h = f2bf(v);
            unsigned short l = f2bf(v - bf2f(h));
            if (FINAL) {
                // stash h2 in LDS (Ah/Al dead: a1 regs loaded before the fq-loop barriers)
                ((unsigned short*)Ah)[lrow * 136 + f] = h;
                ((unsigned short*)Al)[lrow * 136 + f] = l;
            } else if (nrow < N_NODES) {
                Ohi[(size_t)nrow * D + f] = h;
                Olo[(size_t)nrow * D + f] = l;
            }
        }
    }

    if (!FINAL) return;

    // ---- phase 3: classifier GEMM (48 cols) + log_softmax ----
    __syncthreads();   // h2 LDS complete
    bf16x8 a3h[4], a3l[4];
    #pragma unroll
    for (int ks = 0; ks < 4; ks++) {
        int ad = (g * 16 + m) * 136 + ks * 32 + quad * 8;
        a3h[ks] = *(const bf16x8*)((const unsigned short*)Ah + ad);
        a3l[ks] = *(const bf16x8*)((const unsigned short*)Al + ad);
    }
    // tp=0 -> tiles 0,1 (cols 0..31); tp=1 -> tile 2 (cols 32..47)
    const int ntiles = (tp == 0) ? 2 : 1;
    float res[2][4];
    #pragma unroll
    for (int t = 0; t < 2; t++) {
        if (t >= ntiles) break;
        int nt = (tp == 0) ? t : 2;
        int f = nt * 16 + m;
        const unsigned short* whirow = WLhi + (size_t)f * 256 + quad * 8;
        const unsigned short* wlorow = WLlo + (size_t)f * 256 + quad * 8;
        f32x4 acc = {0.f, 0.f, 0.f, 0.f};
        #pragma unroll
        for (int ks = 0; ks < 8; ks++) {
            bf16x8 bh = *(const bf16x8*)(whirow + ks * 32);
            bf16x8 bl = *(const bf16x8*)(wlorow + ks * 32);
            bf16x8 ah = (ks < 4) ? a2h[ks] : a3h[ks - 4];   // A = [h1 | h2]
            bf16x8 al = (ks < 4) ? a2l[ks] : a3l[ks - 4];
            acc = __builtin_amdgcn_mfma_f32_16x16x32_bf16(ah, bh, acc, 0, 0, 0);
            acc = __builtin_amdgcn_mfma_f32_16x16x32_bf16(ah, bl, acc, 0, 0, 0);
            acc = __builtin_amdgcn_mfma_f32_16x16x32_bf16(al, bh, acc, 0, 0, 0);
        }
        float bv = (f < 40) ? blin[f] : 0.f;
        #pragma unroll
        for (int r = 0; r < 4; r++) res[t][r] = acc[r] + bv;
    }
    #pragma unroll
    for (int r = 0; r < 4; r++) {
        float pm = -INFINITY;
        #pragma unroll
        for (int t = 0; t < 2; t++) {
            if (t >= ntiles) break;
            int f = ((tp == 0) ? t : 2) * 16 + m;
            if (f < 40) pm = fmaxf(pm, res[t][r]);
        }
        #pragma unroll
        for (int o = 8; o > 0; o >>= 1) pm = fmaxf(pm, __shfl_xor(pm, o, 64));
        if (m == 0) stats[tp * 64 + g * 16 + quad * 4 + r] = pm;
    }
    __syncthreads();
    float gm[4];
    #pragma unroll
    for (int r = 0; r < 4; r++) {
        int row = g * 16 + quad * 4 + r;
        gm[r] = fmaxf(stats[row], stats[64 + row]);
        float ps = 0.f;
        #pragma unroll
        for (int t = 0; t < 2; t++) {
            if (t >= ntiles) break;
            int f = ((tp == 0) ? t : 2) * 16 + m;
            if (f < 40) ps += expf(res[t][r] - gm[r]);
        }
        #pragma unroll
        for (int o = 8; o > 0; o >>= 1) ps += __shfl_xor(ps, o, 64);
        if (m == 0) stats[128 + tp * 64 + row] = ps;
    }
    __syncthreads();
    #pragma unroll
    for (int r = 0; r < 4; r++) {
        int row = g * 16 + quad * 4 + r;
        int nrow = nb0 + row;
        if (nrow >= N_NODES) continue;
        float lse = gm[r] + logf(stats[128 + row] + stats[192 + row]);
        #pragma unroll
        for (int t = 0; t < 2; t++) {
            if (t >= ntiles) break;
            int f = ((tp == 0) ? t : 2) * 16 + m;
            if (f < 40) out[(size_t)nrow * 40 + f] = res[t][r] - lse;
        }
    }
}

extern "C" void kernel_launch(void* const* d_in, const int* in_sizes, int n_in,
                              void* d_out, int out_size, void* d_ws, size_t ws_size,
                              hipStream_t stream) {
    const float* x     = (const float*)d_in[0];
    const int*   ei    = (const int*)d_in[1];
    const int*   src   = ei;
    const int*   dst   = ei + N_EDGES;
    const float* W1_l  = (const float*)d_in[2];
    const float* b1_l  = (const float*)d_in[3];
    const float* W1_r  = (const float*)d_in[4];
    const float* W2_l  = (const float*)d_in[5];
    const float* b2_l  = (const float*)d_in[6];
    const float* W2_r  = (const float*)d_in[7];
    const float* W_lin = (const float*)d_in[8];
    const float* b_lin = (const float*)d_in[9];
    float* out = (float*)d_out;

    const size_t nd = (size_t)N_NODES * D;
    unsigned short* xhi  = (unsigned short*)d_ws;
    unsigned short* xlo  = xhi + nd;
    unsigned short* h1hi = xlo + nd;
    unsigned short* h1lo = h1hi + nd;
    unsigned short* W1hi = h1lo + nd;                // 128*256 bf16 each
    unsigned short* W1lo = W1hi + 128 * 256;
    unsigned short* W2hi = W1lo + 128 * 256;
    unsigned short* W2lo = W2hi + 128 * 256;
    unsigned short* WLhi = W2lo + 128 * 256;         // 48*256
    unsigned short* WLlo = WLhi + 48 * 256;
    int* deg    = (int*)(WLlo + 48 * 256);
    int* rowptr = deg + N_NODES;
    int* cursor = rowptr + N_NODES + 1;
    int* srcs_sorted = cursor + N_NODES;
    int* bsum   = srcs_sorted + N_EDGES;             // NBLK ints

    // ---- prep (casts/splits) + degree histogram in one dispatch ----
    hipMemsetAsync(deg, 0, N_NODES * sizeof(int), stream);
    prep_deg_kernel<<<9551, 256, 0, stream>>>(dst, deg, x, W1_l, W1_r, W2_l, W2_r, W_lin,
                                              xhi, xlo, W1hi, W1lo, W2hi, W2lo, WLhi, WLlo);

    // ---- CSR build ----
    scan_partial<<<NBLK, 256, 0, stream>>>(deg, bsum);
    scan_write<<<NBLK, 256, 0, stream>>>(deg, bsum, rowptr, cursor);
    bucket_kernel<<<(N_EDGES + 255) / 256, 256, 0, stream>>>(src, dst, cursor, srcs_sorted);

    const int lblk = (N_NODES + 63) / 64;

    // ---- layer 1: gather(x) + GEMM -> h1 planes ----
    fused_layer<false><<<lblk, 512, 0, stream>>>(srcs_sorted, rowptr, xhi, xhi, xlo,
                                                 W1hi, W1lo, b1_l, h1hi, h1lo,
                                                 nullptr, nullptr, nullptr, nullptr);
    // ---- layer 2 + classifier + log_softmax (h2 stays in LDS) ----
    fused_layer<true><<<lblk, 512, 0, stream>>>(srcs_sorted, rowptr, h1hi, h1hi, h1lo,
                                                W2hi, W2lo, b2_l, nullptr, nullptr,
                                                WLhi, WLlo, b_lin, out);
}

// Round 13
// 369.399 us; speedup vs baseline: 1.5616x; 1.0100x over previous
//
#include <hip/hip_runtime.h>
#include <math.h>

#define N_NODES 50000
#define N_EDGES 800000
#define D 128
#define NBLK 196   // ceil(N_NODES/256)

typedef __attribute__((ext_vector_type(8))) short bf16x8;
typedef __attribute__((ext_vector_type(4))) float f32x4;

static __device__ __forceinline__ unsigned short f2bf(float f) {
    unsigned int u = __float_as_uint(f);
    u = (u + 0x7fffu + ((u >> 16) & 1u)) >> 16;
    return (unsigned short)u;
}
static __device__ __forceinline__ float bf2f(unsigned short h) {
    return __uint_as_float(((unsigned int)h) << 16);
}

// ---------------- fused prep: degree histogram + split x + weight split-casts ----------------
__global__ void prep_deg_kernel(const int* __restrict__ dst, int* __restrict__ deg,
                                const float* __restrict__ x,
                                const float* __restrict__ W1l, const float* __restrict__ W1r,
                                const float* __restrict__ W2l, const float* __restrict__ W2r,
                                const float* __restrict__ Wlin,
                                unsigned short* __restrict__ xhi, unsigned short* __restrict__ xlo,
                                unsigned short* __restrict__ W1hi, unsigned short* __restrict__ W1lo,
                                unsigned short* __restrict__ W2hi, unsigned short* __restrict__ W2lo,
                                unsigned short* __restrict__ WLhi, unsigned short* __restrict__ WLlo) {
    int b = blockIdx.x, tid = threadIdx.x;
    if (b < 3125) {
        int e = b * 256 + tid;
        atomicAdd(&deg[dst[e]], 1);
    } else if (b < 9375) {
        int i = ((b - 3125) * 256 + tid) * 4;
        float4 v = *(const float4*)(x + i);
        ushort4 h, l;
        h.x = f2bf(v.x); l.x = f2bf(v.x - bf2f(h.x));
        h.y = f2bf(v.y); l.y = f2bf(v.y - bf2f(h.y));
        h.z = f2bf(v.z); l.z = f2bf(v.z - bf2f(h.z));
        h.w = f2bf(v.w); l.w = f2bf(v.w - bf2f(h.w));
        *(ushort4*)(xhi + i) = h;
        *(ushort4*)(xlo + i) = l;
    } else if (b < 9503) {
        int isW2 = (b >= 9439);
        const float* A = isW2 ? W2l : W1l;
        const float* B = isW2 ? W2r : W1r;
        unsigned short* hi = isW2 ? W2hi : W1hi;
        unsigned short* lo = isW2 ? W2lo : W1lo;
        int f = (b - (isW2 ? 9439 : 9375)) * 2 + (tid >> 7);
        int t = tid & 127;
        float va = A[f * 128 + t], vb = B[f * 128 + t];
        unsigned short ha = f2bf(va), hb = f2bf(vb);
        hi[f * 256 + t]       = ha;
        hi[f * 256 + 128 + t] = hb;
        lo[f * 256 + t]       = f2bf(va - bf2f(ha));
        lo[f * 256 + 128 + t] = f2bf(vb - bf2f(hb));
    } else {
        int f = b - 9503;
        float v = (f < 40) ? Wlin[f * 256 + tid] : 0.f;
        unsigned short h = f2bf(v);
        WLhi[f * 256 + tid] = h;
        WLlo[f * 256 + tid] = f2bf(v - bf2f(h));
    }
}

// ---------------- 2-stage scan ----------------
__global__ void scan_partial(const int* __restrict__ deg, int* __restrict__ bsum) {
    __shared__ int wt[4];
    int tid = threadIdx.x, lane = tid & 63, wv = tid >> 6;
    int idx = blockIdx.x * 256 + tid;
    int v = (idx < N_NODES) ? deg[idx] : 0;
    int s = v;
    #pragma unroll
    for (int o = 1; o < 64; o <<= 1) s += __shfl_xor(s, o, 64);
    if (lane == 0) wt[wv] = s;
    __syncthreads();
    if (tid == 0) bsum[blockIdx.x] = wt[0] + wt[1] + wt[2] + wt[3];
}

__global__ void scan_write(const int* __restrict__ deg, const int* __restrict__ bsum,
                           int* __restrict__ rowptr, int* __restrict__ cursor) {
    __shared__ int wt[4], wt2[4];
    int tid = threadIdx.x, lane = tid & 63, wv = tid >> 6;
    int v0 = (tid < blockIdx.x) ? bsum[tid] : 0;   // blockIdx.x <= 195 < 256
    int s0 = v0;
    #pragma unroll
    for (int o = 1; o < 64; o <<= 1) s0 += __shfl_xor(s0, o, 64);
    if (lane == 0) wt2[wv] = s0;
    int idx = blockIdx.x * 256 + tid;
    int v = (idx < N_NODES) ? deg[idx] : 0;
    int s = v;
    #pragma unroll
    for (int o = 1; o < 64; o <<= 1) { int t = __shfl_up(s, o, 64); if (lane >= o) s += t; }
    if (lane == 63) wt[wv] = s;
    __syncthreads();
    int boff = wt2[0] + wt2[1] + wt2[2] + wt2[3];
    #pragma unroll
    for (int w = 0; w < 4; w++) boff += (w < wv) ? wt[w] : 0;
    int excl = boff + s - v;
    if (idx < N_NODES) { rowptr[idx] = excl; cursor[idx] = excl; }
    if (idx == 0) rowptr[N_NODES] = N_EDGES;
}

// ---------------- bucket edges by dst ----------------
__global__ void bucket_kernel(const int* __restrict__ src, const int* __restrict__ dst,
                              int* __restrict__ cursor, int* __restrict__ srcs_sorted) {
    int e = blockIdx.x * blockDim.x + threadIdx.x;
    if (e < N_EDGES) {
        int pos = atomicAdd(&cursor[dst[e]], 1);
        srcs_sorted[pos] = src[e];
    }
}

// ---------------- fused layer: gather-mean (LDS) + split-bf16 MFMA GEMM ----------------
// Block = 512 thr (8 waves) = 64 nodes x 128 outputs. LDS 51 KB.
// Gather: 2 independent node streams interleaved per wave (static uA/uB buffers —
// round-11's dynamically-indexed dbuf spilled to scratch). Every batch is the
// proven clamp+mask 16-batch; branches are wave-uniform.
// FINAL=true additionally fuses the 40-col classifier + log_softmax (h2 never hits HBM).
template<bool FINAL>
__global__ __launch_bounds__(512, 4) void fused_layer(
    const int* __restrict__ srcs, const int* __restrict__ rowptr,
    const unsigned short* __restrict__ Shi,                                     // gather source hi
    const unsigned short* __restrict__ A2hi, const unsigned short* __restrict__ A2lo,  // self planes
    const unsigned short* __restrict__ Whi, const unsigned short* __restrict__ Wlo,    // [128,256]
    const float* __restrict__ bias,
    unsigned short* __restrict__ Ohi, unsigned short* __restrict__ Olo,         // layer out (if !FINAL)
    const unsigned short* __restrict__ WLhi, const unsigned short* __restrict__ WLlo,  // [48,256]
    const float* __restrict__ blin, float* __restrict__ out)                    // (if FINAL)
{
    __shared__ unsigned int Ah[64 * 68];       // 17408 B (agg hi; reused as h2 hi if FINAL)
    __shared__ unsigned int Al[64 * 68];       // 17408 B
    __shared__ unsigned short Wl[8192];        // 16 KB (Whi quarter stage)
    __shared__ float stats[256];               // 1 KB softmax stats (FINAL)

    const int tid = threadIdx.x;
    const int wv = tid >> 6, lane = tid & 63;
    const int nb0 = blockIdx.x * 64;

    // ---- phase 1: gather-mean into LDS, 2-node interleaved streams ----
    const unsigned int* xp = (const unsigned int*)Shi;   // row = 64 dwords
    #pragma unroll 1
    for (int it = 0; it < 4; it++) {
        int nlA = it * 16 + wv, nlB = nlA + 8;
        int nodeA = min(nb0 + nlA, N_NODES - 1);
        int nodeB = min(nb0 + nlB, N_NODES - 1);
        int begA = rowptr[nodeA], endA = rowptr[nodeA + 1];
        int begB = rowptr[nodeB], endB = rowptr[nodeB + 1];
        int nA = (endA - begA + 15) >> 4;
        int nB = (endB - begB + 15) >> 4;
        int nmax = max(nA, nB);
        float axA[4] = {0,0,0,0}, ayA[4] = {0,0,0,0};
        float axB[4] = {0,0,0,0}, ayB[4] = {0,0,0,0};
        #pragma unroll 1
        for (int b = 0; b < nmax; b++) {
            unsigned int uA[16], uB[16];
            int baseA = begA + b * 16, baseB = begB + b * 16;
            if (b < nA) {
                #pragma unroll
                for (int j = 0; j < 16; j++) {
                    int ee = min(baseA + j, endA - 1);
                    uA[j] = xp[(size_t)srcs[ee] * 64 + lane];
                }
            }
            if (b < nB) {
                #pragma unroll
                for (int j = 0; j < 16; j++) {
                    int ee = min(baseB + j, endB - 1);
                    uB[j] = xp[(size_t)srcs[ee] * 64 + lane];
                }
            }
            if (b < nA) {
                int cA = min(16, endA - baseA);
                #pragma unroll
                for (int j = 0; j < 16; j++) {
                    if (j < cA) {
                        axA[j & 3] += __uint_as_float(uA[j] << 16);
                        ayA[j & 3] += __uint_as_float(uA[j] & 0xffff0000u);
                    }
                }
            }
            if (b < nB) {
                int cB = min(16, endB - baseB);
                #pragma unroll
                for (int j = 0; j < 16; j++) {
                    if (j < cB) {
                        axB[j & 3] += __uint_as_float(uB[j] << 16);
                        ayB[j & 3] += __uint_as_float(uB[j] & 0xffff0000u);
                    }
                }
            }
        }
        // flush A
        {
            float sx = (axA[0] + axA[1]) + (axA[2] + axA[3]);
            float sy = (ayA[0] + ayA[1]) + (ayA[2] + ayA[3]);
            float inv = 1.0f / fmaxf((float)(endA - begA), 1.0f);
            sx *= inv; sy *= inv;
            unsigned short h0 = f2bf(sx), h1 = f2bf(sy);
            unsigned short l0 = f2bf(sx - bf2f(h0)), l1 = f2bf(sy - bf2f(h1));
            Ah[nlA * 68 + lane] = (unsigned int)h0 | ((unsigned int)h1 << 16);
            Al[nlA * 68 + lane] = (unsigned int)l0 | ((unsigned int)l1 << 16);
        }
        // flush B
        {
            float sx = (axB[0] + axB[1]) + (axB[2] + axB[3]);
            float sy = (ayB[0] + ayB[1]) + (ayB[2] + ayB[3]);
            float inv = 1.0f / fmaxf((float)(endB - begB), 1.0f);
            sx *= inv; sy *= inv;
            unsigned short h0 = f2bf(sx), h1 = f2bf(sy);
            unsigned short l0 = f2bf(sx - bf2f(h0)), l1 = f2bf(sy - bf2f(h1));
            Ah[nlB * 68 + lane] = (unsigned int)h0 | ((unsigned int)h1 << 16);
            Al[nlB * 68 + lane] = (unsigned int)l0 | ((unsigned int)l1 << 16);
        }
    }
    __syncthreads();   // A tiles ready

    const int m = lane & 15, quad = lane >> 4;
    const int g = wv & 3, tp = wv >> 2;
    const int node_base = nb0 + g * 16;
    const int nodec = min(node_base + m, N_NODES - 1);

    // A1 frags (agg, K 0..127) from LDS; A2 frags (self, K 128..255) from global
    bf16x8 a1h[4], a1l[4], a2h[4], a2l[4];
    {
        const unsigned short* r2h = A2hi + (size_t)nodec * D + quad * 8;
        const unsigned short* r2l = A2lo + (size_t)nodec * D + quad * 8;
        #pragma unroll
        for (int ks = 0; ks < 4; ks++) {
            a2h[ks] = *(const bf16x8*)(r2h + ks * 32);
            a2l[ks] = *(const bf16x8*)(r2l + ks * 32);
        }
        #pragma unroll
        for (int ks = 0; ks < 4; ks++) {
            int ad = ((g * 16 + m) * 68 + quad * 4 + ks * 16) * 2;   // ushort offset
            a1h[ks] = *(const bf16x8*)((const unsigned short*)Ah + ad);
            a1l[ks] = *(const bf16x8*)((const unsigned short*)Al + ad);
        }
    }

    // ---- phase 2: GEMM over 4 f-quarters (Whi staged 16 KB at a time) ----
    #pragma unroll 1
    for (int fq = 0; fq < 4; fq++) {
        const int f0 = fq * 32;
        if (fq) __syncthreads();
        #pragma unroll
        for (int itS = 0; itS < 2; itS++) {
            int c = tid + itS * 512;                 // 1024 chunks of 16B
            int nt = c >> 9, w2 = c & 511;
            int ks = w2 >> 6, lidx = w2 & 63;
            int mm = lidx >> 2, qq = lidx & 3;
            const unsigned short* gp = Whi + (size_t)(f0 + nt * 16 + mm) * 256 + ks * 32 + qq * 8;
            *(bf16x8*)&Wl[(size_t)c * 8] = *(const bf16x8*)gp;
        }
        __syncthreads();

        int f = f0 + tp * 16 + m;
        const unsigned short* wlorow = Wlo + (size_t)f * 256 + quad * 8;
        f32x4 acc = {0.f, 0.f, 0.f, 0.f};
        #pragma unroll
        for (int ks = 0; ks < 8; ks++) {
            bf16x8 bh = *(const bf16x8*)&Wl[(size_t)(((tp * 8 + ks) << 6) + (m * 4 + quad)) * 8];
            bf16x8 bl = *(const bf16x8*)(wlorow + ks * 32);
            bf16x8 ah = (ks < 4) ? a1h[ks] : a2h[ks - 4];
            bf16x8 al = (ks < 4) ? a1l[ks] : a2l[ks - 4];
            acc = __builtin_amdgcn_mfma_f32_16x16x32_bf16(ah, bh, acc, 0, 0, 0);
            acc = __builtin_amdgcn_mfma_f32_16x16x32_bf16(ah, bl, acc, 0, 0, 0);
            acc = __builtin_amdgcn_mfma_f32_16x16x32_bf16(al, bh, acc, 0, 0, 0);
        }
        float bv = bias[f];
        #pragma unroll
        for (int r = 0; r < 4; r++) {
            int lrow = g * 16 + quad * 4 + r;
            int nrow = nb0 + lrow;
            float v = fmaxf(acc[r] + bv, 0.f);
            unsigned short h = f2bf(v);
            unsigned short l = f2bf(v - bf2f(h));
            if (FINAL) {
                // stash h2 in LDS (Ah/Al dead: a1 regs loaded before the fq-loop barriers)
                ((unsigned short*)Ah)[lrow * 136 + f] = h;
                ((unsigned short*)Al)[lrow * 136 + f] = l;
            } else if (nrow < N_NODES) {
                Ohi[(size_t)nrow * D + f] = h;
                Olo[(size_t)nrow * D + f] = l;
            }
        }
    }

    if (!FINAL) return;

    // ---- phase 3: classifier GEMM (48 cols) + log_softmax ----
    __syncthreads();   // h2 LDS complete
    bf16x8 a3h[4], a3l[4];
    #pragma unroll
    for (int ks = 0; ks < 4; ks++) {
        int ad = (g * 16 + m) * 136 + ks * 32 + quad * 8;
        a3h[ks] = *(const bf16x8*)((const unsigned short*)Ah + ad);
        a3l[ks] = *(const bf16x8*)((const unsigned short*)Al + ad);
    }
    // tp=0 -> tiles 0,1 (cols 0..31); tp=1 -> tile 2 (cols 32..47)
    const int ntiles = (tp == 0) ? 2 : 1;
    float res[2][4];
    #pragma unroll
    for (int t = 0; t < 2; t++) {
        if (t >= ntiles) break;
        int nt = (tp == 0) ? t : 2;
        int f = nt * 16 + m;
        const unsigned short* whirow = WLhi + (size_t)f * 256 + quad * 8;
        const unsigned short* wlorow = WLlo + (size_t)f * 256 + quad * 8;
        f32x4 acc = {0.f, 0.f, 0.f, 0.f};
        #pragma unroll
        for (int ks = 0; ks < 8; ks++) {
            bf16x8 bh = *(const bf16x8*)(whirow + ks * 32);
            bf16x8 bl = *(const bf16x8*)(wlorow + ks * 32);
            bf16x8 ah = (ks < 4) ? a2h[ks] : a3h[ks - 4];   // A = [h1 | h2]
            bf16x8 al = (ks < 4) ? a2l[ks] : a3l[ks - 4];
            acc = __builtin_amdgcn_mfma_f32_16x16x32_bf16(ah, bh, acc, 0, 0, 0);
            acc = __builtin_amdgcn_mfma_f32_16x16x32_bf16(ah, bl, acc, 0, 0, 0);
            acc = __builtin_amdgcn_mfma_f32_16x16x32_bf16(al, bh, acc, 0, 0, 0);
        }
        float bv = (f < 40) ? blin[f] : 0.f;
        #pragma unroll
        for (int r = 0; r < 4; r++) res[t][r] = acc[r] + bv;
    }
    #pragma unroll
    for (int r = 0; r < 4; r++) {
        float pm = -INFINITY;
        #pragma unroll
        for (int t = 0; t < 2; t++) {
            if (t >= ntiles) break;
            int f = ((tp == 0) ? t : 2) * 16 + m;
            if (f < 40) pm = fmaxf(pm, res[t][r]);
        }
        #pragma unroll
        for (int o = 8; o > 0; o >>= 1) pm = fmaxf(pm, __shfl_xor(pm, o, 64));
        if (m == 0) stats[tp * 64 + g * 16 + quad * 4 + r] = pm;
    }
    __syncthreads();
    float gm[4];
    #pragma unroll
    for (int r = 0; r < 4; r++) {
        int row = g * 16 + quad * 4 + r;
        gm[r] = fmaxf(stats[row], stats[64 + row]);
        float ps = 0.f;
        #pragma unroll
        for (int t = 0; t < 2; t++) {
            if (t >= ntiles) break;
            int f = ((tp == 0) ? t : 2) * 16 + m;
            if (f < 40) ps += expf(res[t][r] - gm[r]);
        }
        #pragma unroll
        for (int o = 8; o > 0; o >>= 1) ps += __shfl_xor(ps, o, 64);
        if (m == 0) stats[128 + tp * 64 + row] = ps;
    }
    __syncthreads();
    #pragma unroll
    for (int r = 0; r < 4; r++) {
        int row = g * 16 + quad * 4 + r;
        int nrow = nb0 + row;
        if (nrow >= N_NODES) continue;
        float lse = gm[r] + logf(stats[128 + row] + stats[192 + row]);
        #pragma unroll
        for (int t = 0; t < 2; t++) {
            if (t >= ntiles) break;
            int f = ((tp == 0) ? t : 2) * 16 + m;
            if (f < 40) out[(size_t)nrow * 40 + f] = res[t][r] - lse;
        }
    }
}

extern "C" void kernel_launch(void* const* d_in, const int* in_sizes, int n_in,
                              void* d_out, int out_size, void* d_ws, size_t ws_size,
                              hipStream_t stream) {
    const float* x     = (const float*)d_in[0];
    const int*   ei    = (const int*)d_in[1];
    const int*   src   = ei;
    const int*   dst   = ei + N_EDGES;
    const float* W1_l  = (const float*)d_in[2];
    const float* b1_l  = (const float*)d_in[3];
    const float* W1_r  = (const float*)d_in[4];
    const float* W2_l  = (const float*)d_in[5];
    const float* b2_l  = (const float*)d_in[6];
    const float* W2_r  = (const float*)d_in[7];
    const float* W_lin = (const float*)d_in[8];
    const float* b_lin = (const float*)d_in[9];
    float* out = (float*)d_out;

    const size_t nd = (size_t)N_NODES * D;
    unsigned short* xhi  = (unsigned short*)d_ws;
    unsigned short* xlo  = xhi + nd;
    unsigned short* h1hi = xlo + nd;
    unsigned short* h1lo = h1hi + nd;
    unsigned short* W1hi = h1lo + nd;                // 128*256 bf16 each
    unsigned short* W1lo = W1hi + 128 * 256;
    unsigned short* W2hi = W1lo + 128 * 256;
    unsigned short* W2lo = W2hi + 128 * 256;
    unsigned short* WLhi = W2lo + 128 * 256;         // 48*256
    unsigned short* WLlo = WLhi + 48 * 256;
    int* deg    = (int*)(WLlo + 48 * 256);
    int* rowptr = deg + N_NODES;
    int* cursor = rowptr + N_NODES + 1;
    int* srcs_sorted = cursor + N_NODES;
    int* bsum   = srcs_sorted + N_EDGES;             // NBLK ints

    // ---- prep (casts/splits) + degree histogram in one dispatch ----
    hipMemsetAsync(deg, 0, N_NODES * sizeof(int), stream);
    prep_deg_kernel<<<9551, 256, 0, stream>>>(dst, deg, x, W1_l, W1_r, W2_l, W2_r, W_lin,
                                              xhi, xlo, W1hi, W1lo, W2hi, W2lo, WLhi, WLlo);

    // ---- CSR build ----
    scan_partial<<<NBLK, 256, 0, stream>>>(deg, bsum);
    scan_write<<<NBLK, 256, 0, stream>>>(deg, bsum, rowptr, cursor);
    bucket_kernel<<<(N_EDGES + 255) / 256, 256, 0, stream>>>(src, dst, cursor, srcs_sorted);

    const int lblk = (N_NODES + 63) / 64;

    // ---- layer 1: gather(x) + GEMM -> h1 planes ----
    fused_layer<false><<<lblk, 512, 0, stream>>>(srcs_sorted, rowptr, xhi, xhi, xlo,
                                                 W1hi, W1lo, b1_l, h1hi, h1lo,
                                                 nullptr, nullptr, nullptr, nullptr);
    // ---- layer 2 + classifier + log_softmax (h2 stays in LDS) ----
    fused_layer<true><<<lblk, 512, 0, stream>>>(srcs_sorted, rowptr, h1hi, h1hi, h1lo,
                                                W2hi, W2lo, b2_l, nullptr, nullptr,
                                                WLhi, WLlo, b_lin, out);
}

// Round 14
// 331.676 us; speedup vs baseline: 1.7392x; 1.1137x over previous
//
#include <hip/hip_runtime.h>
#include <math.h>

#define N_NODES 50000
#define N_EDGES 800000
#define D 128
#define NBLK 196   // ceil(N_NODES/256)

typedef __attribute__((ext_vector_type(8))) short bf16x8;
typedef __attribute__((ext_vector_type(4))) float f32x4;

static __device__ __forceinline__ unsigned short f2bf(float f) {
    unsigned int u = __float_as_uint(f);
    u = (u + 0x7fffu + ((u >> 16) & 1u)) >> 16;
    return (unsigned short)u;
}
static __device__ __forceinline__ float bf2f(unsigned short h) {
    return __uint_as_float(((unsigned int)h) << 16);
}

// ---------------- fused prep: degree+rank histogram + split x + weight split-casts ----------------
__global__ void prep_deg_kernel(const int* __restrict__ dst, int* __restrict__ deg,
                                int* __restrict__ rank,
                                const float* __restrict__ x,
                                const float* __restrict__ W1l, const float* __restrict__ W1r,
                                const float* __restrict__ W2l, const float* __restrict__ W2r,
                                const float* __restrict__ Wlin,
                                unsigned short* __restrict__ xhi, unsigned short* __restrict__ xlo,
                                unsigned short* __restrict__ W1hi, unsigned short* __restrict__ W1lo,
                                unsigned short* __restrict__ W2hi, unsigned short* __restrict__ W2lo,
                                unsigned short* __restrict__ WLhi, unsigned short* __restrict__ WLlo) {
    int b = blockIdx.x, tid = threadIdx.x;
    if (b < 3125) {
        int e = b * 256 + tid;
        rank[e] = atomicAdd(&deg[dst[e]], 1);   // rank within dst bucket
    } else if (b < 9375) {
        int i = ((b - 3125) * 256 + tid) * 4;
        float4 v = *(const float4*)(x + i);
        ushort4 h, l;
        h.x = f2bf(v.x); l.x = f2bf(v.x - bf2f(h.x));
        h.y = f2bf(v.y); l.y = f2bf(v.y - bf2f(h.y));
        h.z = f2bf(v.z); l.z = f2bf(v.z - bf2f(h.z));
        h.w = f2bf(v.w); l.w = f2bf(v.w - bf2f(h.w));
        *(ushort4*)(xhi + i) = h;
        *(ushort4*)(xlo + i) = l;
    } else if (b < 9503) {
        int isW2 = (b >= 9439);
        const float* A = isW2 ? W2l : W1l;
        const float* B = isW2 ? W2r : W1r;
        unsigned short* hi = isW2 ? W2hi : W1hi;
        unsigned short* lo = isW2 ? W2lo : W1lo;
        int f = (b - (isW2 ? 9439 : 9375)) * 2 + (tid >> 7);
        int t = tid & 127;
        float va = A[f * 128 + t], vb = B[f * 128 + t];
        unsigned short ha = f2bf(va), hb = f2bf(vb);
        hi[f * 256 + t]       = ha;
        hi[f * 256 + 128 + t] = hb;
        lo[f * 256 + t]       = f2bf(va - bf2f(ha));
        lo[f * 256 + 128 + t] = f2bf(vb - bf2f(hb));
    } else {
        int f = b - 9503;
        float v = (f < 40) ? Wlin[f * 256 + tid] : 0.f;
        unsigned short h = f2bf(v);
        WLhi[f * 256 + tid] = h;
        WLlo[f * 256 + tid] = f2bf(v - bf2f(h));
    }
}

// ---------------- 2-stage scan ----------------
__global__ void scan_partial(const int* __restrict__ deg, int* __restrict__ bsum) {
    __shared__ int wt[4];
    int tid = threadIdx.x, lane = tid & 63, wv = tid >> 6;
    int idx = blockIdx.x * 256 + tid;
    int v = (idx < N_NODES) ? deg[idx] : 0;
    int s = v;
    #pragma unroll
    for (int o = 1; o < 64; o <<= 1) s += __shfl_xor(s, o, 64);
    if (lane == 0) wt[wv] = s;
    __syncthreads();
    if (tid == 0) bsum[blockIdx.x] = wt[0] + wt[1] + wt[2] + wt[3];
}

__global__ void scan_write(const int* __restrict__ deg, const int* __restrict__ bsum,
                           int* __restrict__ rowptr) {
    __shared__ int wt[4], wt2[4];
    int tid = threadIdx.x, lane = tid & 63, wv = tid >> 6;
    int v0 = (tid < blockIdx.x) ? bsum[tid] : 0;   // blockIdx.x <= 195 < 256
    int s0 = v0;
    #pragma unroll
    for (int o = 1; o < 64; o <<= 1) s0 += __shfl_xor(s0, o, 64);
    if (lane == 0) wt2[wv] = s0;
    int idx = blockIdx.x * 256 + tid;
    int v = (idx < N_NODES) ? deg[idx] : 0;
    int s = v;
    #pragma unroll
    for (int o = 1; o < 64; o <<= 1) { int t = __shfl_up(s, o, 64); if (lane >= o) s += t; }
    if (lane == 63) wt[wv] = s;
    __syncthreads();
    int boff = wt2[0] + wt2[1] + wt2[2] + wt2[3];
    #pragma unroll
    for (int w = 0; w < 4; w++) boff += (w < wv) ? wt[w] : 0;
    int excl = boff + s - v;
    if (idx < N_NODES) rowptr[idx] = excl;
    if (idx == 0) rowptr[N_NODES] = N_EDGES;
}

// ---------------- bucket edges by dst (atomic-free: pos = rowptr[dst] + rank) ----------------
__global__ void bucket_kernel(const int* __restrict__ src, const int* __restrict__ dst,
                              const int* __restrict__ rowptr, const int* __restrict__ rank,
                              int* __restrict__ srcs_sorted) {
    int e = blockIdx.x * blockDim.x + threadIdx.x;
    if (e < N_EDGES) {
        srcs_sorted[rowptr[dst[e]] + rank[e]] = src[e];
    }
}

// ---------------- fused layer: gather-mean (LDS) + split-bf16 MFMA GEMM ----------------
// Block = 512 thr (8 waves) = 64 nodes x 128 outputs. LDS 51 KB.
// Gather: 2 interleaved node streams, clamp+mask 16-batches (static buffers).
// GEMM: 3 INDEPENDENT MFMA accumulator chains (hi*hi, hi*lo, lo*hi) — round-6's
// single-acc merge serialized 24 dependent MFMAs; this restores 3x ILP.
// FINAL=true additionally fuses the 40-col classifier + log_softmax (h2 never hits HBM).
template<bool FINAL>
__global__ __launch_bounds__(512, 4) void fused_layer(
    const int* __restrict__ srcs, const int* __restrict__ rowptr,
    const unsigned short* __restrict__ Shi,                                     // gather source hi
    const unsigned short* __restrict__ A2hi, const unsigned short* __restrict__ A2lo,  // self planes
    const unsigned short* __restrict__ Whi, const unsigned short* __restrict__ Wlo,    // [128,256]
    const float* __restrict__ bias,
    unsigned short* __restrict__ Ohi, unsigned short* __restrict__ Olo,         // layer out (if !FINAL)
    const unsigned short* __restrict__ WLhi, const unsigned short* __restrict__ WLlo,  // [48,256]
    const float* __restrict__ blin, float* __restrict__ out)                    // (if FINAL)
{
    __shared__ unsigned int Ah[64 * 68];       // 17408 B (agg hi; reused as h2 hi if FINAL)
    __shared__ unsigned int Al[64 * 68];       // 17408 B
    __shared__ unsigned short Wl[8192];        // 16 KB (Whi quarter stage)
    __shared__ float stats[256];               // 1 KB softmax stats (FINAL)

    const int tid = threadIdx.x;
    const int wv = tid >> 6, lane = tid & 63;
    const int nb0 = blockIdx.x * 64;

    // ---- phase 1: gather-mean into LDS, 2-node interleaved streams ----
    const unsigned int* xp = (const unsigned int*)Shi;   // row = 64 dwords
    #pragma unroll 1
    for (int it = 0; it < 4; it++) {
        int nlA = it * 16 + wv, nlB = nlA + 8;
        int nodeA = min(nb0 + nlA, N_NODES - 1);
        int nodeB = min(nb0 + nlB, N_NODES - 1);
        int begA = rowptr[nodeA], endA = rowptr[nodeA + 1];
        int begB = rowptr[nodeB], endB = rowptr[nodeB + 1];
        int nA = (endA - begA + 15) >> 4;
        int nB = (endB - begB + 15) >> 4;
        int nmax = max(nA, nB);
        float axA[4] = {0,0,0,0}, ayA[4] = {0,0,0,0};
        float axB[4] = {0,0,0,0}, ayB[4] = {0,0,0,0};
        #pragma unroll 1
        for (int b = 0; b < nmax; b++) {
            unsigned int uA[16], uB[16];
            int baseA = begA + b * 16, baseB = begB + b * 16;
            if (b < nA) {
                #pragma unroll
                for (int j = 0; j < 16; j++) {
                    int ee = min(baseA + j, endA - 1);
                    uA[j] = xp[(size_t)srcs[ee] * 64 + lane];
                }
            }
            if (b < nB) {
                #pragma unroll
                for (int j = 0; j < 16; j++) {
                    int ee = min(baseB + j, endB - 1);
                    uB[j] = xp[(size_t)srcs[ee] * 64 + lane];
                }
            }
            if (b < nA) {
                int cA = min(16, endA - baseA);
                #pragma unroll
                for (int j = 0; j < 16; j++) {
                    if (j < cA) {
                        axA[j & 3] += __uint_as_float(uA[j] << 16);
                        ayA[j & 3] += __uint_as_float(uA[j] & 0xffff0000u);
                    }
                }
            }
            if (b < nB) {
                int cB = min(16, endB - baseB);
                #pragma unroll
                for (int j = 0; j < 16; j++) {
                    if (j < cB) {
                        axB[j & 3] += __uint_as_float(uB[j] << 16);
                        ayB[j & 3] += __uint_as_float(uB[j] & 0xffff0000u);
                    }
                }
            }
        }
        {
            float sx = (axA[0] + axA[1]) + (axA[2] + axA[3]);
            float sy = (ayA[0] + ayA[1]) + (ayA[2] + ayA[3]);
            float inv = 1.0f / fmaxf((float)(endA - begA), 1.0f);
            sx *= inv; sy *= inv;
            unsigned short h0 = f2bf(sx), h1 = f2bf(sy);
            unsigned short l0 = f2bf(sx - bf2f(h0)), l1 = f2bf(sy - bf2f(h1));
            Ah[nlA * 68 + lane] = (unsigned int)h0 | ((unsigned int)h1 << 16);
            Al[nlA * 68 + lane] = (unsigned int)l0 | ((unsigned int)l1 << 16);
        }
        {
            float sx = (axB[0] + axB[1]) + (axB[2] + axB[3]);
            float sy = (ayB[0] + ayB[1]) + (ayB[2] + ayB[3]);
            float inv = 1.0f / fmaxf((float)(endB - begB), 1.0f);
            sx *= inv; sy *= inv;
            unsigned short h0 = f2bf(sx), h1 = f2bf(sy);
            unsigned short l0 = f2bf(sx - bf2f(h0)), l1 = f2bf(sy - bf2f(h1));
            Ah[nlB * 68 + lane] = (unsigned int)h0 | ((unsigned int)h1 << 16);
            Al[nlB * 68 + lane] = (unsigned int)l0 | ((unsigned int)l1 << 16);
        }
    }
    __syncthreads();   // A tiles ready

    const int m = lane & 15, quad = lane >> 4;
    const int g = wv & 3, tp = wv >> 2;
    const int node_base = nb0 + g * 16;
    const int nodec = min(node_base + m, N_NODES - 1);

    // A1 frags (agg, K 0..127) from LDS; A2 frags (self, K 128..255) from global
    bf16x8 a1h[4], a1l[4], a2h[4], a2l[4];
    {
        const unsigned short* r2h = A2hi + (size_t)nodec * D + quad * 8;
        const unsigned short* r2l = A2lo + (size_t)nodec * D + quad * 8;
        #pragma unroll
        for (int ks = 0; ks < 4; ks++) {
            a2h[ks] = *(const bf16x8*)(r2h + ks * 32);
            a2l[ks] = *(const bf16x8*)(r2l + ks * 32);
        }
        #pragma unroll
        for (int ks = 0; ks < 4; ks++) {
            int ad = ((g * 16 + m) * 68 + quad * 4 + ks * 16) * 2;   // ushort offset
            a1h[ks] = *(const bf16x8*)((const unsigned short*)Ah + ad);
            a1l[ks] = *(const bf16x8*)((const unsigned short*)Al + ad);
        }
    }

    // ---- phase 2: GEMM over 4 f-quarters (Whi staged 16 KB at a time) ----
    #pragma unroll 1
    for (int fq = 0; fq < 4; fq++) {
        const int f0 = fq * 32;
        if (fq) __syncthreads();
        #pragma unroll
        for (int itS = 0; itS < 2; itS++) {
            int c = tid + itS * 512;                 // 1024 chunks of 16B
            int nt = c >> 9, w2 = c & 511;
            int ks = w2 >> 6, lidx = w2 & 63;
            int mm = lidx >> 2, qq = lidx & 3;
            const unsigned short* gp = Whi + (size_t)(f0 + nt * 16 + mm) * 256 + ks * 32 + qq * 8;
            *(bf16x8*)&Wl[(size_t)c * 8] = *(const bf16x8*)gp;
        }
        __syncthreads();

        int f = f0 + tp * 16 + m;
        const unsigned short* wlorow = Wlo + (size_t)f * 256 + quad * 8;
        f32x4 acc0 = {0.f, 0.f, 0.f, 0.f};
        f32x4 acc1 = {0.f, 0.f, 0.f, 0.f};
        f32x4 acc2 = {0.f, 0.f, 0.f, 0.f};
        #pragma unroll
        for (int ks = 0; ks < 8; ks++) {
            bf16x8 bh = *(const bf16x8*)&Wl[(size_t)(((tp * 8 + ks) << 6) + (m * 4 + quad)) * 8];
            bf16x8 bl = *(const bf16x8*)(wlorow + ks * 32);
            bf16x8 ah = (ks < 4) ? a1h[ks] : a2h[ks - 4];
            bf16x8 al = (ks < 4) ? a1l[ks] : a2l[ks - 4];
            acc0 = __builtin_amdgcn_mfma_f32_16x16x32_bf16(ah, bh, acc0, 0, 0, 0);
            acc1 = __builtin_amdgcn_mfma_f32_16x16x32_bf16(ah, bl, acc1, 0, 0, 0);
            acc2 = __builtin_amdgcn_mfma_f32_16x16x32_bf16(al, bh, acc2, 0, 0, 0);
        }
        float bv = bias[f];
        #pragma unroll
        for (int r = 0; r < 4; r++) {
            int lrow = g * 16 + quad * 4 + r;
            int nrow = nb0 + lrow;
            float v = fmaxf((acc0[r] + (acc1[r] + acc2[r])) + bv, 0.f);
            unsigned short h = f2bf(v);
            unsigned short l = f2bf(v - bf2f(h));
            if (FINAL) {
                // stash h2 in LDS (Ah/Al dead: a1 regs loaded before the fq-loop barriers)
                ((unsigned short*)Ah)[lrow * 136 + f] = h;
                ((unsigned short*)Al)[lrow * 136 + f] = l;
            } else if (nrow < N_NODES) {
                Ohi[(size_t)nrow * D + f] = h;
                Olo[(size_t)nrow * D + f] = l;
            }
        }
    }

    if (!FINAL) return;

    // ---- phase 3: classifier GEMM (48 cols) + log_softmax ----
    __syncthreads();   // h2 LDS complete
    bf16x8 a3h[4], a3l[4];
    #pragma unroll
    for (int ks = 0; ks < 4; ks++) {
        int ad = (g * 16 + m) * 136 + ks * 32 + quad * 8;
        a3h[ks] = *(const bf16x8*)((const unsigned short*)Ah + ad);
        a3l[ks] = *(const bf16x8*)((const unsigned short*)Al + ad);
    }
    // tp=0 -> tiles 0,1 (cols 0..31); tp=1 -> tile 2 (cols 32..47)
    const int ntiles = (tp == 0) ? 2 : 1;
    float res[2][4];
    #pragma unroll
    for (int t = 0; t < 2; t++) {
        if (t >= ntiles) break;
        int nt = (tp == 0) ? t : 2;
        int f = nt * 16 + m;
        const unsigned short* whirow = WLhi + (size_t)f * 256 + quad * 8;
        const unsigned short* wlorow = WLlo + (size_t)f * 256 + quad * 8;
        f32x4 acc0 = {0.f, 0.f, 0.f, 0.f};
        f32x4 acc1 = {0.f, 0.f, 0.f, 0.f};
        f32x4 acc2 = {0.f, 0.f, 0.f, 0.f};
        #pragma unroll
        for (int ks = 0; ks < 8; ks++) {
            bf16x8 bh = *(const bf16x8*)(whirow + ks * 32);
            bf16x8 bl = *(const bf16x8*)(wlorow + ks * 32);
            bf16x8 ah = (ks < 4) ? a2h[ks] : a3h[ks - 4];   // A = [h1 | h2]
            bf16x8 al = (ks < 4) ? a2l[ks] : a3l[ks - 4];
            acc0 = __builtin_amdgcn_mfma_f32_16x16x32_bf16(ah, bh, acc0, 0, 0, 0);
            acc1 = __builtin_amdgcn_mfma_f32_16x16x32_bf16(ah, bl, acc1, 0, 0, 0);
            acc2 = __builtin_amdgcn_mfma_f32_16x16x32_bf16(al, bh, acc2, 0, 0, 0);
        }
        float bv = (f < 40) ? blin[f] : 0.f;
        #pragma unroll
        for (int r = 0; r < 4; r++) res[t][r] = (acc0[r] + (acc1[r] + acc2[r])) + bv;
    }
    #pragma unroll
    for (int r = 0; r < 4; r++) {
        float pm = -INFINITY;
        #pragma unroll
        for (int t = 0; t < 2; t++) {
            if (t >= ntiles) break;
            int f = ((tp == 0) ? t : 2) * 16 + m;
            if (f < 40) pm = fmaxf(pm, res[t][r]);
        }
        #pragma unroll
        for (int o = 8; o > 0; o >>= 1) pm = fmaxf(pm, __shfl_xor(pm, o, 64));
        if (m == 0) stats[tp * 64 + g * 16 + quad * 4 + r] = pm;
    }
    __syncthreads();
    float gm[4];
    #pragma unroll
    for (int r = 0; r < 4; r++) {
        int row = g * 16 + quad * 4 + r;
        gm[r] = fmaxf(stats[row], stats[64 + row]);
        float ps = 0.f;
        #pragma unroll
        for (int t = 0; t < 2; t++) {
            if (t >= ntiles) break;
            int f = ((tp == 0) ? t : 2) * 16 + m;
            if (f < 40) ps += expf(res[t][r] - gm[r]);
        }
        #pragma unroll
        for (int o = 8; o > 0; o >>= 1) ps += __shfl_xor(ps, o, 64);
        if (m == 0) stats[128 + tp * 64 + row] = ps;
    }
    __syncthreads();
    #pragma unroll
    for (int r = 0; r < 4; r++) {
        int row = g * 16 + quad * 4 + r;
        int nrow = nb0 + row;
        if (nrow >= N_NODES) continue;
        float lse = gm[r] + logf(stats[128 + row] + stats[192 + row]);
        #pragma unroll
        for (int t = 0; t < 2; t++) {
            if (t >= ntiles) break;
            int f = ((tp == 0) ? t : 2) * 16 + m;
            if (f < 40) out[(size_t)nrow * 40 + f] = res[t][r] - lse;
        }
    }
}

extern "C" void kernel_launch(void* const* d_in, const int* in_sizes, int n_in,
                              void* d_out, int out_size, void* d_ws, size_t ws_size,
                              hipStream_t stream) {
    const float* x     = (const float*)d_in[0];
    const int*   ei    = (const int*)d_in[1];
    const int*   src   = ei;
    const int*   dst   = ei + N_EDGES;
    const float* W1_l  = (const float*)d_in[2];
    const float* b1_l  = (const float*)d_in[3];
    const float* W1_r  = (const float*)d_in[4];
    const float* W2_l  = (const float*)d_in[5];
    const float* b2_l  = (const float*)d_in[6];
    const float* W2_r  = (const float*)d_in[7];
    const float* W_lin = (const float*)d_in[8];
    const float* b_lin = (const float*)d_in[9];
    float* out = (float*)d_out;

    const size_t nd = (size_t)N_NODES * D;
    unsigned short* xhi  = (unsigned short*)d_ws;
    unsigned short* xlo  = xhi + nd;
    unsigned short* h1hi = xlo + nd;
    unsigned short* h1lo = h1hi + nd;
    unsigned short* W1hi = h1lo + nd;                // 128*256 bf16 each
    unsigned short* W1lo = W1hi + 128 * 256;
    unsigned short* W2hi = W1lo + 128 * 256;
    unsigned short* W2lo = W2hi + 128 * 256;
    unsigned short* WLhi = W2lo + 128 * 256;         // 48*256
    unsigned short* WLlo = WLhi + 48 * 256;
    int* deg    = (int*)(WLlo + 48 * 256);
    int* rowptr = deg + N_NODES;                     // N_NODES+1
    int* rank   = rowptr + N_NODES + 1;              // N_EDGES
    int* srcs_sorted = rank + N_EDGES;               // N_EDGES
    int* bsum   = srcs_sorted + N_EDGES;             // NBLK

    // ---- prep (casts/splits) + degree/rank histogram in one dispatch ----
    hipMemsetAsync(deg, 0, N_NODES * sizeof(int), stream);
    prep_deg_kernel<<<9551, 256, 0, stream>>>(dst, deg, rank, x, W1_l, W1_r, W2_l, W2_r, W_lin,
                                              xhi, xlo, W1hi, W1lo, W2hi, W2lo, WLhi, WLlo);

    // ---- CSR build ----
    scan_partial<<<NBLK, 256, 0, stream>>>(deg, bsum);
    scan_write<<<NBLK, 256, 0, stream>>>(deg, bsum, rowptr);
    bucket_kernel<<<(N_EDGES + 255) / 256, 256, 0, stream>>>(src, dst, rowptr, rank, srcs_sorted);

    const int lblk = (N_NODES + 63) / 64;

    // ---- layer 1: gather(x) + GEMM -> h1 planes ----
    fused_layer<false><<<lblk, 512, 0, stream>>>(srcs_sorted, rowptr, xhi, xhi, xlo,
                                                 W1hi, W1lo, b1_l, h1hi, h1lo,
                                                 nullptr, nullptr, nullptr, nullptr);
    // ---- layer 2 + classifier + log_softmax (h2 stays in LDS) ----
    fused_layer<true><<<lblk, 512, 0, stream>>>(srcs_sorted, rowptr, h1hi, h1hi, h1lo,
                                                W2hi, W2lo, b2_l, nullptr, nullptr,
                                                WLhi, WLlo, b_lin, out);
}